// Round 1
// baseline (14498.994 us; speedup 1.0000x reference)
//
#include <hip/hip_runtime.h>

// Problem constants
#define TT 128
#define BB 16
#define HH 1024
#define EE 1024
#define VV 32000
#define G4 4096   // 4*H

using short8  = __attribute__((ext_vector_type(8))) short;
using floatx4 = __attribute__((ext_vector_type(4))) float;

__device__ __forceinline__ unsigned short f2bf(float f) {
    union { float f; unsigned u; } v; v.f = f;
    unsigned r = v.u + 0x7fffu + ((v.u >> 16) & 1u);
    return (unsigned short)(r >> 16);
}
__device__ __forceinline__ float bf2f(unsigned short u) {
    union { unsigned u; float f; } v; v.u = ((unsigned)u) << 16;
    return v.f;
}

// ---------------- fp32 -> bf16 plain cast, 4 elems/thread ----------------
__global__ void cast_bf(const float* __restrict__ src, unsigned short* __restrict__ dst, int n4) {
    int i = blockIdx.x * blockDim.x + threadIdx.x;
    if (i >= n4) return;
    float4 f = *(const float4*)(src + (size_t)i * 4);
    ushort4 o;
    o.x = f2bf(f.x); o.y = f2bf(f.y); o.z = f2bf(f.z); o.w = f2bf(f.w);
    *(ushort4*)(dst + (size_t)i * 4) = o;
}

// ---------------- fp32 -> (hi, lo) bf16 split cast, 4 elems/thread ----------------
__global__ void cast_split(const float* __restrict__ src, unsigned short* __restrict__ hi,
                           unsigned short* __restrict__ lo, int n4) {
    int i = blockIdx.x * blockDim.x + threadIdx.x;
    if (i >= n4) return;
    float4 f = *(const float4*)(src + (size_t)i * 4);
    ushort4 h, l;
    h.x = f2bf(f.x); l.x = f2bf(f.x - bf2f(h.x));
    h.y = f2bf(f.y); l.y = f2bf(f.y - bf2f(h.y));
    h.z = f2bf(f.z); l.z = f2bf(f.z - bf2f(h.z));
    h.w = f2bf(f.w); l.w = f2bf(f.w - bf2f(h.w));
    *(ushort4*)(hi + (size_t)i * 4) = h;
    *(ushort4*)(lo + (size_t)i * 4) = l;
}

// ---------------- embedding gather + split cast: x[t*16+b][e] ----------------
__global__ void gather_embed(const int* __restrict__ ids, const float* __restrict__ embed,
                             unsigned short* __restrict__ xhi, unsigned short* __restrict__ xlo) {
    int idx = blockIdx.x * blockDim.x + threadIdx.x;   // 2048*128 threads, 8 elems each
    int row = idx >> 7;              // t*16 + b
    int e0  = (idx & 127) << 3;
    int t = row >> 4, b = row & 15;
    int id = ids[b * TT + t];        // input_ids is [B, T]
    const float* s = embed + (size_t)id * EE + e0;
    float4 f0 = *(const float4*)s;
    float4 f1 = *(const float4*)(s + 4);
    float f[8] = {f0.x, f0.y, f0.z, f0.w, f1.x, f1.y, f1.z, f1.w};
    union { unsigned short u[8]; int4 v; } oh, ol;
#pragma unroll
    for (int j = 0; j < 8; ++j) {
        oh.u[j] = f2bf(f[j]);
        ol.u[j] = f2bf(f[j] - bf2f(oh.u[j]));
    }
    *(int4*)(xhi + (size_t)row * EE + e0) = oh.v;
    *(int4*)(xlo + (size_t)row * EE + e0) = ol.v;
}

// ---------------- state init (runs every call; ws is re-poisoned) ----------------
// grid 256x256 = 65536 threads
__global__ void init_state(const float* __restrict__ ench, const float* __restrict__ encc,
                           float* __restrict__ c0, float* __restrict__ c1,
                           unsigned short* __restrict__ h0ah, unsigned short* __restrict__ h0al,
                           unsigned short* __restrict__ h1ih, unsigned short* __restrict__ h1il,
                           unsigned short* __restrict__ zrow,
                           float* __restrict__ gacc, int* __restrict__ cnt) {
    int i = blockIdx.x * blockDim.x + threadIdx.x;   // 65536
    gacc[i] = 0.f;                                   // layer-1 gate accumulator [16,4096]
    if (i < 128) cnt[i] = 0;                         // completion counters (2 x 64)
    if (i >= 16384) return;
    c0[i] = encc[i];
    c1[i] = encc[16384 + i];
    float h0 = ench[i], h1 = ench[16384 + i];
    unsigned short h0h = f2bf(h0), h1h = f2bf(h1);
    h0ah[i] = h0h; h0al[i] = f2bf(h0 - bf2f(h0h));
    h1ih[i] = h1h; h1il[i] = f2bf(h1 - bf2f(h1h));
    zrow[i] = 0;
}

// ---------------- bf16 MFMA GEMM: C[M,N] = A[M,K] @ B[N,K]^T (+bias) ----------------
// Optional hi/lo split on A and/or B (3-product compensation).
// wave tile 16m x 64n, 4 waves on m -> block tile 64m x 64n.
// C/D: lane/reg r -> row = quad*4 + r, col = lane&15.
// outmode 0: row-major [M,N].  outmode 1: feats row m=t*16+b -> out[(b*TT+t)*N + n].
template<bool SA, bool SB>
__global__ void gemm_bt(const unsigned short* __restrict__ Ah, const unsigned short* __restrict__ Al, int lda,
                        const unsigned short* __restrict__ Bh, const unsigned short* __restrict__ Bl, int ldb,
                        float* __restrict__ C,
                        const float* __restrict__ bias1, const float* __restrict__ bias2,
                        int N, int K, int outmode) {
    int tid = threadIdx.x;
    int wave = tid >> 6, lane = tid & 63;
    int quad = lane >> 4, mcol = lane & 15;
    int m0 = blockIdx.x * 64 + wave * 16;
    int n0 = blockIdx.y * 64;
    floatx4 acc[4] = {};
    size_t aoff = (size_t)(m0 + mcol) * lda + quad * 8;
    size_t boff = (size_t)(n0 + mcol) * ldb + quad * 8;
    for (int k = 0; k < K; k += 32) {
        short8 ah = *(const short8*)(Ah + aoff + k);
        short8 al;
        if (SA) al = *(const short8*)(Al + aoff + k);
#pragma unroll
        for (int g = 0; g < 4; ++g) {
            size_t bo = boff + (size_t)g * 16 * ldb + k;
            short8 bh = *(const short8*)(Bh + bo);
            acc[g] = __builtin_amdgcn_mfma_f32_16x16x32_bf16(ah, bh, acc[g], 0, 0, 0);
            if (SB) {
                short8 bl = *(const short8*)(Bl + bo);
                acc[g] = __builtin_amdgcn_mfma_f32_16x16x32_bf16(ah, bl, acc[g], 0, 0, 0);
            }
            if (SA)
                acc[g] = __builtin_amdgcn_mfma_f32_16x16x32_bf16(al, bh, acc[g], 0, 0, 0);
        }
    }
#pragma unroll
    for (int g = 0; g < 4; ++g) {
#pragma unroll
        for (int r = 0; r < 4; ++r) {
            int m = m0 + quad * 4 + r;
            int n = n0 + g * 16 + mcol;
            float v = acc[g][r];
            if (bias1) v += bias1[n];
            if (bias2) v += bias2[n];
            size_t off;
            if (outmode == 0) off = (size_t)m * N + n;
            else { int t = m >> 4, b = m & 15; off = (size_t)(b * TT + t) * N + n; }
            C[off] = v;
        }
    }
}

// ---------------- one LSTM half-step, K-split across the full GPU ----------------
// grid 512 blocks x 256 threads. Block (ug = bid&63, kq = bid>>6):
//   16 hidden units u0=ug*16 across all 4 gates, K-slice [kq*128, kq*128+128).
//   Waves 0,1: matmul-1 K-64ths; waves 2,3: matmul-2. LDS reduce -> atomicAdd
//   partial gates into gacc (fp32, device-scope).
// Last-arriving block per ug (counter) runs the pointwise cell for its 16 units
// and resets the accumulator (layer 1) / counter in-kernel: still 2 launches/step.
__global__ void lstm_gates(const unsigned short* __restrict__ A1h, const unsigned short* __restrict__ A1l,
                           const unsigned short* __restrict__ B1h, const unsigned short* __restrict__ B1l, int ldb1,
                           const unsigned short* __restrict__ A2h, const unsigned short* __restrict__ A2l,
                           const unsigned short* __restrict__ B2h, const unsigned short* __restrict__ B2l, int ldb2,
                           float* __restrict__ gacc,
                           const float* __restrict__ bi1, const float* __restrict__ bi2,
                           float* __restrict__ cstate,
                           unsigned short* __restrict__ houth, unsigned short* __restrict__ houtl,
                           int* __restrict__ cnt, int zero_acc) {
    __shared__ float red[4][4][64][4];   // [wave][gate][lane][reg] = 16 KB
    __shared__ int lastflag;
    int tid = threadIdx.x, wave = tid >> 6, lane = tid & 63;
    int quad = lane >> 4, mcol = lane & 15;
    int ug = blockIdx.x & 63;
    int kq = blockIdx.x >> 6;            // 0..7
    int u0 = ug * 16;
    const unsigned short* Ah = (wave < 2) ? A1h : A2h;
    const unsigned short* Al = (wave < 2) ? A1l : A2l;
    const unsigned short* Bh = (wave < 2) ? B1h : B2h;
    const unsigned short* Bl = (wave < 2) ? B1l : B2l;
    int ldb   = (wave < 2) ? ldb1 : ldb2;
    int kbase = kq * 128 + (wave & 1) * 64;
    floatx4 acc[4] = {};
    size_t aoff = (size_t)mcol * HH + kbase + quad * 8;
    size_t boff = (size_t)(u0 + mcol) * ldb + kbase + quad * 8;
#pragma unroll
    for (int k = 0; k < 64; k += 32) {
        short8 ah = *(const short8*)(Ah + aoff + k);
        short8 al = *(const short8*)(Al + aoff + k);
#pragma unroll
        for (int g = 0; g < 4; ++g) {
            size_t bo = boff + (size_t)g * 1024 * ldb + k;
            short8 bh = *(const short8*)(Bh + bo);
            short8 bl = *(const short8*)(Bl + bo);
            acc[g] = __builtin_amdgcn_mfma_f32_16x16x32_bf16(ah, bh, acc[g], 0, 0, 0);
            acc[g] = __builtin_amdgcn_mfma_f32_16x16x32_bf16(ah, bl, acc[g], 0, 0, 0);
            acc[g] = __builtin_amdgcn_mfma_f32_16x16x32_bf16(al, bh, acc[g], 0, 0, 0);
        }
    }
#pragma unroll
    for (int g = 0; g < 4; ++g)
        *(floatx4*)&red[wave][g][lane][0] = acc[g];
    __syncthreads();
    {   // wave w handles gate w: 4 atomic adds per lane
        int g = wave;
#pragma unroll
        for (int r = 0; r < 4; ++r) {
            float s = red[0][g][lane][r] + red[1][g][lane][r]
                    + red[2][g][lane][r] + red[3][g][lane][r];
            atomicAdd(&gacc[(size_t)(quad * 4 + r) * G4 + g * 1024 + u0 + mcol], s);
        }
    }
    __threadfence();                     // release: my partial sums are globally visible
    __syncthreads();
    if (tid == 0) lastflag = (atomicAdd(&cnt[ug], 1) == 7);
    __syncthreads();
    if (!lastflag) return;
    __threadfence();                     // acquire: see all 8 blocks' partial sums
    // pointwise cell: 256 threads = 16 batch rows x 16 units
    int row = tid >> 4, ui = tid & 15, u = u0 + ui;
    float gv[4];
#pragma unroll
    for (int gi = 0; gi < 4; ++gi) {
        float* p = &gacc[(size_t)row * G4 + gi * 1024 + u];
        float v = __hip_atomic_load(p, __ATOMIC_RELAXED, __HIP_MEMORY_SCOPE_AGENT);
        if (bi1) v += bi1[gi * 1024 + u] + bi2[gi * 1024 + u];
        gv[gi] = v;
        if (zero_acc)
            __hip_atomic_store(p, 0.f, __ATOMIC_RELAXED, __HIP_MEMORY_SCOPE_AGENT);
    }
    float cold = cstate[(size_t)row * HH + u];
    float si = 1.f / (1.f + __expf(-gv[0]));
    float sf = 1.f / (1.f + __expf(-gv[1]));
    float tg = tanhf(gv[2]);
    float so = 1.f / (1.f + __expf(-gv[3]));
    float cn = sf * cold + si * tg;
    float hn = so * tanhf(cn);
    cstate[(size_t)row * HH + u] = cn;
    size_t hoff = (size_t)row * HH + u;
    unsigned short hh = f2bf(hn);
    houth[hoff] = hh;
    houtl[hoff] = f2bf(hn - bf2f(hh));
    if (tid == 0) cnt[ug] = 0;           // reset for next step (kernel-boundary flush)
}

extern "C" void kernel_launch(void* const* d_in, const int* in_sizes, int n_in,
                              void* d_out, int out_size, void* d_ws, size_t ws_size,
                              hipStream_t stream) {
    const int*   ids   = (const int*)d_in[0];
    const float* ench  = (const float*)d_in[1];
    const float* encc  = (const float*)d_in[2];
    const float* embed = (const float*)d_in[3];
    const float* Wih0  = (const float*)d_in[4];
    const float* Whh0  = (const float*)d_in[5];
    const float* bih0  = (const float*)d_in[6];
    const float* bhh0  = (const float*)d_in[7];
    const float* Wih1  = (const float*)d_in[8];
    const float* Whh1  = (const float*)d_in[9];
    const float* bih1  = (const float*)d_in[10];
    const float* bhh1  = (const float*)d_in[11];
    const float* Wout  = (const float*)d_in[12];
    const float* bout  = (const float*)d_in[13];
    float* out = (float*)d_out;
    (void)in_sizes; (void)n_in; (void)out_size; (void)ws_size;

    // workspace layout (deterministic bump allocator, 256B aligned)
    char* ws = (char*)d_ws;
    size_t o = 0;
    auto alloc = [&](size_t bytes) { size_t r = o; o += (bytes + 255) & ~(size_t)255; return r; };
    unsigned short* wih0_hi = (unsigned short*)(ws + alloc((size_t)G4 * (EE + HH) * 2));
    unsigned short* wih0_lo = (unsigned short*)(ws + alloc((size_t)G4 * (EE + HH) * 2));
    unsigned short* whh0_hi = (unsigned short*)(ws + alloc((size_t)G4 * HH * 2));
    unsigned short* whh0_lo = (unsigned short*)(ws + alloc((size_t)G4 * HH * 2));
    unsigned short* wih1_hi = (unsigned short*)(ws + alloc((size_t)G4 * HH * 2));
    unsigned short* wih1_lo = (unsigned short*)(ws + alloc((size_t)G4 * HH * 2));
    unsigned short* whh1_hi = (unsigned short*)(ws + alloc((size_t)G4 * HH * 2));
    unsigned short* whh1_lo = (unsigned short*)(ws + alloc((size_t)G4 * HH * 2));
    unsigned short* wout_hi = (unsigned short*)(ws + alloc((size_t)VV * HH * 2));
    unsigned short* x_hi    = (unsigned short*)(ws + alloc((size_t)TT * BB * EE * 2));
    unsigned short* x_lo    = (unsigned short*)(ws + alloc((size_t)TT * BB * EE * 2));
    float*          xproj   = (float*)(ws + alloc((size_t)TT * BB * G4 * 4));
    unsigned short* feats_hi = (unsigned short*)(ws + alloc((size_t)TT * BB * HH * 2));
    unsigned short* feats_lo = (unsigned short*)(ws + alloc((size_t)TT * BB * HH * 2));
    float*          c0      = (float*)(ws + alloc((size_t)BB * HH * 4));
    float*          c1      = (float*)(ws + alloc((size_t)BB * HH * 4));
    unsigned short* h0a_hi  = (unsigned short*)(ws + alloc((size_t)BB * HH * 2));
    unsigned short* h0a_lo  = (unsigned short*)(ws + alloc((size_t)BB * HH * 2));
    unsigned short* h0b_hi  = (unsigned short*)(ws + alloc((size_t)BB * HH * 2));
    unsigned short* h0b_lo  = (unsigned short*)(ws + alloc((size_t)BB * HH * 2));
    unsigned short* h1i_hi  = (unsigned short*)(ws + alloc((size_t)BB * HH * 2));
    unsigned short* h1i_lo  = (unsigned short*)(ws + alloc((size_t)BB * HH * 2));
    unsigned short* zrow    = (unsigned short*)(ws + alloc((size_t)BB * HH * 2));
    float*          gacc    = (float*)(ws + alloc((size_t)BB * G4 * 4));
    int*            cnt     = (int*)(ws + alloc(128 * 4));   // [0:64)=layer0, [64:128)=layer1

    // 1) split-cast recurrence weights; plain-cast Wout
    cast_split<<<(2097152 + 255) / 256, 256, 0, stream>>>(Wih0, wih0_hi, wih0_lo, 2097152);
    cast_split<<<(1048576 + 255) / 256, 256, 0, stream>>>(Whh0, whh0_hi, whh0_lo, 1048576);
    cast_split<<<(1048576 + 255) / 256, 256, 0, stream>>>(Wih1, wih1_hi, wih1_lo, 1048576);
    cast_split<<<(1048576 + 255) / 256, 256, 0, stream>>>(Whh1, whh1_hi, whh1_lo, 1048576);
    cast_bf<<<(8192000 + 255) / 256, 256, 0, stream>>>(Wout, wout_hi, 8192000);

    // 2) embedding gather + split cast
    gather_embed<<<(TT * BB * EE / 8) / 256, 256, 0, stream>>>(ids, embed, x_hi, x_lo);

    // 3) state init (+ gate accumulator + counters)
    init_state<<<256, 256, 0, stream>>>(ench, encc, c0, c1, h0a_hi, h0a_lo, h1i_hi, h1i_lo,
                                        zrow, gacc, cnt);

    // 4) hoisted input projection: xproj = x @ Wih0[:, :E]^T + bih0 + bhh0  (split x split)
    gemm_bt<true, true><<<dim3(2048 / 64, G4 / 64), 256, 0, stream>>>(
        x_hi, x_lo, EE, wih0_hi, wih0_lo, EE + HH, xproj, bih0, bhh0, G4, EE, 0);

    // 5) sequential recurrence: 2 launches per step, each on the full GPU (512 blocks)
    for (int t = 0; t < TT; ++t) {
        const unsigned short* feedh = (t == 0) ? zrow : feats_hi + (size_t)(t - 1) * BB * HH;
        const unsigned short* feedl = (t == 0) ? zrow : feats_lo + (size_t)(t - 1) * BB * HH;
        const unsigned short* h0rdh = (t & 1) ? h0b_hi : h0a_hi;
        const unsigned short* h0rdl = (t & 1) ? h0b_lo : h0a_lo;
        unsigned short*       h0wrh = (t & 1) ? h0a_hi : h0b_hi;
        unsigned short*       h0wrl = (t & 1) ? h0a_lo : h0b_lo;
        // layer 0: gates = xproj[t] (acc) + feed @ Wih0[:,E:]^T + h0 @ Whh0^T
        lstm_gates<<<512, 256, 0, stream>>>(feedh, feedl, wih0_hi + 1024, wih0_lo + 1024, EE + HH,
                                            h0rdh, h0rdl, whh0_hi, whh0_lo, HH,
                                            xproj + (size_t)t * BB * G4, nullptr, nullptr,
                                            c0, h0wrh, h0wrl, cnt, 0);
        // layer 1: gates = h0_new @ Wih1^T + h1_prev @ Whh1^T + bih1 + bhh1
        const unsigned short* h1rdh = (t == 0) ? h1i_hi : feats_hi + (size_t)(t - 1) * BB * HH;
        const unsigned short* h1rdl = (t == 0) ? h1i_lo : feats_lo + (size_t)(t - 1) * BB * HH;
        lstm_gates<<<512, 256, 0, stream>>>(h0wrh, h0wrl, wih1_hi, wih1_lo, HH,
                                            h1rdh, h1rdl, whh1_hi, whh1_lo, HH,
                                            gacc, bih1, bhh1,
                                            c1, feats_hi + (size_t)t * BB * HH, feats_lo + (size_t)t * BB * HH,
                                            cnt + 64, 1);
    }

    // 6) output projection: logits[b,t,:] = feats[t*16+b] @ Wout^T + bout   (plain bf16)
    gemm_bt<false, false><<<dim3(2048 / 64, VV / 64), 256, 0, stream>>>(
        feats_hi, nullptr, HH, wout_hi, nullptr, HH, out, bout, nullptr, VV, HH, 1);
}

// Round 2
// 14442.154 us; speedup vs baseline: 1.0039x; 1.0039x over previous
//
#include <hip/hip_runtime.h>

// Problem constants
#define TT 128
#define BB 16
#define HH 1024
#define EE 1024
#define VV 32000
#define G4 4096   // 4*H

using short8  = __attribute__((ext_vector_type(8))) short;
using floatx4 = __attribute__((ext_vector_type(4))) float;

__device__ __forceinline__ unsigned short f2bf(float f) {
    union { float f; unsigned u; } v; v.f = f;
    unsigned r = v.u + 0x7fffu + ((v.u >> 16) & 1u);
    return (unsigned short)(r >> 16);
}
__device__ __forceinline__ float bf2f(unsigned short u) {
    union { unsigned u; float f; } v; v.u = ((unsigned)u) << 16;
    return v.f;
}

// ---------------- fp32 -> bf16 plain cast, 4 elems/thread ----------------
__global__ void cast_bf(const float* __restrict__ src, unsigned short* __restrict__ dst, int n4) {
    int i = blockIdx.x * blockDim.x + threadIdx.x;
    if (i >= n4) return;
    float4 f = *(const float4*)(src + (size_t)i * 4);
    ushort4 o;
    o.x = f2bf(f.x); o.y = f2bf(f.y); o.z = f2bf(f.z); o.w = f2bf(f.w);
    *(ushort4*)(dst + (size_t)i * 4) = o;
}

// ---------------- fp32 -> (hi, lo) bf16 split cast, 4 elems/thread ----------------
__global__ void cast_split(const float* __restrict__ src, unsigned short* __restrict__ hi,
                           unsigned short* __restrict__ lo, int n4) {
    int i = blockIdx.x * blockDim.x + threadIdx.x;
    if (i >= n4) return;
    float4 f = *(const float4*)(src + (size_t)i * 4);
    ushort4 h, l;
    h.x = f2bf(f.x); l.x = f2bf(f.x - bf2f(h.x));
    h.y = f2bf(f.y); l.y = f2bf(f.y - bf2f(h.y));
    h.z = f2bf(f.z); l.z = f2bf(f.z - bf2f(h.z));
    h.w = f2bf(f.w); l.w = f2bf(f.w - bf2f(h.w));
    *(ushort4*)(hi + (size_t)i * 4) = h;
    *(ushort4*)(lo + (size_t)i * 4) = l;
}

// ---------------- embedding gather + split cast: x[t*16+b][e] ----------------
__global__ void gather_embed(const int* __restrict__ ids, const float* __restrict__ embed,
                             unsigned short* __restrict__ xhi, unsigned short* __restrict__ xlo) {
    int idx = blockIdx.x * blockDim.x + threadIdx.x;   // 2048*128 threads, 8 elems each
    int row = idx >> 7;              // t*16 + b
    int e0  = (idx & 127) << 3;
    int t = row >> 4, b = row & 15;
    int id = ids[b * TT + t];        // input_ids is [B, T]
    const float* s = embed + (size_t)id * EE + e0;
    float4 f0 = *(const float4*)s;
    float4 f1 = *(const float4*)(s + 4);
    float f[8] = {f0.x, f0.y, f0.z, f0.w, f1.x, f1.y, f1.z, f1.w};
    union { unsigned short u[8]; int4 v; } oh, ol;
#pragma unroll
    for (int j = 0; j < 8; ++j) {
        oh.u[j] = f2bf(f[j]);
        ol.u[j] = f2bf(f[j] - bf2f(oh.u[j]));
    }
    *(int4*)(xhi + (size_t)row * EE + e0) = oh.v;
    *(int4*)(xlo + (size_t)row * EE + e0) = ol.v;
}

// ---------------- state init (runs every call; ws is re-poisoned) ----------------
__global__ void init_state(const float* __restrict__ ench, const float* __restrict__ encc,
                           float* __restrict__ c0, float* __restrict__ c1,
                           unsigned short* __restrict__ h0ah, unsigned short* __restrict__ h0al,
                           unsigned short* __restrict__ h1ih, unsigned short* __restrict__ h1il,
                           unsigned short* __restrict__ zrow, int* __restrict__ cnt) {
    int i = blockIdx.x * blockDim.x + threadIdx.x;   // 16384
    if (i < 128) cnt[i] = 0;                         // completion counters
    c0[i] = encc[i];
    c1[i] = encc[16384 + i];
    float h0 = ench[i], h1 = ench[16384 + i];
    unsigned short h0h = f2bf(h0), h1h = f2bf(h1);
    h0ah[i] = h0h; h0al[i] = f2bf(h0 - bf2f(h0h));
    h1ih[i] = h1h; h1il[i] = f2bf(h1 - bf2f(h1h));
    zrow[i] = 0;
}

// ---------------- bf16 MFMA GEMM: C[M,N] = A[M,K] @ B[N,K]^T (+bias) ----------------
// Optional hi/lo split on A and/or B (3-product compensation).
// wave tile 16m x 64n, 4 waves on m -> block tile 64m x 64n.
// C/D: lane/reg r -> row = quad*4 + r, col = lane&15.
// outmode 0: row-major [M,N].  outmode 1: feats row m=t*16+b -> out[(b*TT+t)*N + n].
template<bool SA, bool SB>
__global__ void gemm_bt(const unsigned short* __restrict__ Ah, const unsigned short* __restrict__ Al, int lda,
                        const unsigned short* __restrict__ Bh, const unsigned short* __restrict__ Bl, int ldb,
                        float* __restrict__ C,
                        const float* __restrict__ bias1, const float* __restrict__ bias2,
                        int N, int K, int outmode) {
    int tid = threadIdx.x;
    int wave = tid >> 6, lane = tid & 63;
    int quad = lane >> 4, mcol = lane & 15;
    int m0 = blockIdx.x * 64 + wave * 16;
    int n0 = blockIdx.y * 64;
    floatx4 acc[4] = {};
    size_t aoff = (size_t)(m0 + mcol) * lda + quad * 8;
    size_t boff = (size_t)(n0 + mcol) * ldb + quad * 8;
    for (int k = 0; k < K; k += 32) {
        short8 ah = *(const short8*)(Ah + aoff + k);
        short8 al;
        if (SA) al = *(const short8*)(Al + aoff + k);
#pragma unroll
        for (int g = 0; g < 4; ++g) {
            size_t bo = boff + (size_t)g * 16 * ldb + k;
            short8 bh = *(const short8*)(Bh + bo);
            acc[g] = __builtin_amdgcn_mfma_f32_16x16x32_bf16(ah, bh, acc[g], 0, 0, 0);
            if (SB) {
                short8 bl = *(const short8*)(Bl + bo);
                acc[g] = __builtin_amdgcn_mfma_f32_16x16x32_bf16(ah, bl, acc[g], 0, 0, 0);
            }
            if (SA)
                acc[g] = __builtin_amdgcn_mfma_f32_16x16x32_bf16(al, bh, acc[g], 0, 0, 0);
        }
    }
#pragma unroll
    for (int g = 0; g < 4; ++g) {
#pragma unroll
        for (int r = 0; r < 4; ++r) {
            int m = m0 + quad * 4 + r;
            int n = n0 + g * 16 + mcol;
            float v = acc[g][r];
            if (bias1) v += bias1[n];
            if (bias2) v += bias2[n];
            size_t off;
            if (outmode == 0) off = (size_t)m * N + n;
            else { int t = m >> 4, b = m & 15; off = (size_t)(b * TT + t) * N + n; }
            C[off] = v;
        }
    }
}

// ---------------- one LSTM half-step: gate-split across the full GPU ----------------
// grid 256 blocks x 512 threads. Block: gate g = bid>>6, unit-group ug = bid&63
// (the 4 gate-blocks of one ug have bids differing by 64 -> same XCD under
// round-robin dispatch). 8 waves: wave w covers matrix (w>>2) K-quarter (w&3).
// Each block EXCLUSIVELY owns its (g,ug) 16x16 output tile: LDS-reduce 8 waves,
// add base (xproj for layer 0), PLAIN agent-scope store to gbuf — no data atomics.
// Last-arriving of the 4 gate-blocks per ug (1 counter atomic/block) runs the
// pointwise cell for its 16 units and resets the counter.
__global__ void lstm_gates(const unsigned short* __restrict__ A1h, const unsigned short* __restrict__ A1l,
                           const unsigned short* __restrict__ B1h, const unsigned short* __restrict__ B1l, int ldb1,
                           const unsigned short* __restrict__ A2h, const unsigned short* __restrict__ A2l,
                           const unsigned short* __restrict__ B2h, const unsigned short* __restrict__ B2l, int ldb2,
                           const float* __restrict__ base,   // pre-accumulated input (layer0: xproj[t]) or null
                           float* __restrict__ gbuf,         // [16][4096] gate buffer (exclusive stores)
                           const float* __restrict__ bi1, const float* __restrict__ bi2,
                           float* __restrict__ cstate,
                           unsigned short* __restrict__ houth, unsigned short* __restrict__ houtl,
                           int* __restrict__ cnt) {
    __shared__ float red[8][64][4];   // [wave][lane][reg] = 8 KB
    __shared__ int lastflag;
    int tid = threadIdx.x, wave = tid >> 6, lane = tid & 63;
    int quad = lane >> 4, mcol = lane & 15;
    int g  = blockIdx.x >> 6;
    int ug = blockIdx.x & 63;
    int u0 = ug * 16;
    const unsigned short* Ah = (wave < 4) ? A1h : A2h;
    const unsigned short* Al = (wave < 4) ? A1l : A2l;
    const unsigned short* Bh = (wave < 4) ? B1h : B2h;
    const unsigned short* Bl = (wave < 4) ? B1l : B2l;
    int ldb   = (wave < 4) ? ldb1 : ldb2;
    int kbase = (wave & 3) * 256;
    floatx4 acc = {};
    size_t aoff = (size_t)mcol * HH + kbase + quad * 8;
    size_t boff = (size_t)(g * 1024 + u0 + mcol) * ldb + kbase + quad * 8;
#pragma unroll
    for (int k = 0; k < 256; k += 32) {
        short8 ah = *(const short8*)(Ah + aoff + k);
        short8 al = *(const short8*)(Al + aoff + k);
        short8 bh = *(const short8*)(Bh + boff + k);
        short8 bl = *(const short8*)(Bl + boff + k);
        acc = __builtin_amdgcn_mfma_f32_16x16x32_bf16(ah, bh, acc, 0, 0, 0);
        acc = __builtin_amdgcn_mfma_f32_16x16x32_bf16(ah, bl, acc, 0, 0, 0);
        acc = __builtin_amdgcn_mfma_f32_16x16x32_bf16(al, bh, acc, 0, 0, 0);
    }
    *(floatx4*)&red[wave][lane][0] = acc;
    __syncthreads();
    if (tid < 256) {
        // one thread per output element: row = batch, ui = unit-in-group
        int row = tid >> 4, ui = tid & 15;
        int rl = (row >> 2) * 16 + ui, rr = row & 3;   // acc layout: row=quad*4+r, col=mcol
        float s = 0.f;
#pragma unroll
        for (int w = 0; w < 8; ++w) s += red[w][rl][rr];
        int n = g * 1024 + u0 + ui;
        if (base) s += base[(size_t)row * G4 + n];
        __hip_atomic_store(&gbuf[(size_t)row * G4 + n], s,
                           __ATOMIC_RELAXED, __HIP_MEMORY_SCOPE_AGENT);
    }
    __threadfence();                     // release: my tile globally visible
    __syncthreads();
    if (tid == 0) lastflag = (atomicAdd(&cnt[ug], 1) == 3);
    __syncthreads();
    if (!lastflag) return;
    __threadfence();                     // acquire: see all 4 gate tiles
    if (tid < 256) {
        int row = tid >> 4, ui = tid & 15, u = u0 + ui;
        float gv[4];
#pragma unroll
        for (int gi = 0; gi < 4; ++gi) {
            float v = __hip_atomic_load(&gbuf[(size_t)row * G4 + gi * 1024 + u],
                                        __ATOMIC_RELAXED, __HIP_MEMORY_SCOPE_AGENT);
            if (bi1) v += bi1[gi * 1024 + u] + bi2[gi * 1024 + u];
            gv[gi] = v;
        }
        float cold = cstate[(size_t)row * HH + u];
        float si = 1.f / (1.f + __expf(-gv[0]));
        float sf = 1.f / (1.f + __expf(-gv[1]));
        float tg = tanhf(gv[2]);
        float so = 1.f / (1.f + __expf(-gv[3]));
        float cn = sf * cold + si * tg;
        float hn = so * tanhf(cn);
        cstate[(size_t)row * HH + u] = cn;
        size_t hoff = (size_t)row * HH + u;
        unsigned short hh = f2bf(hn);
        houth[hoff] = hh;
        houtl[hoff] = f2bf(hn - bf2f(hh));
    }
    if (tid == 0) cnt[ug] = 0;           // reset for next launch (kernel-boundary flush)
}

extern "C" void kernel_launch(void* const* d_in, const int* in_sizes, int n_in,
                              void* d_out, int out_size, void* d_ws, size_t ws_size,
                              hipStream_t stream) {
    const int*   ids   = (const int*)d_in[0];
    const float* ench  = (const float*)d_in[1];
    const float* encc  = (const float*)d_in[2];
    const float* embed = (const float*)d_in[3];
    const float* Wih0  = (const float*)d_in[4];
    const float* Whh0  = (const float*)d_in[5];
    const float* bih0  = (const float*)d_in[6];
    const float* bhh0  = (const float*)d_in[7];
    const float* Wih1  = (const float*)d_in[8];
    const float* Whh1  = (const float*)d_in[9];
    const float* bih1  = (const float*)d_in[10];
    const float* bhh1  = (const float*)d_in[11];
    const float* Wout  = (const float*)d_in[12];
    const float* bout  = (const float*)d_in[13];
    float* out = (float*)d_out;
    (void)in_sizes; (void)n_in; (void)out_size; (void)ws_size;

    // workspace layout (deterministic bump allocator, 256B aligned)
    char* ws = (char*)d_ws;
    size_t o = 0;
    auto alloc = [&](size_t bytes) { size_t r = o; o += (bytes + 255) & ~(size_t)255; return r; };
    unsigned short* wih0_hi = (unsigned short*)(ws + alloc((size_t)G4 * (EE + HH) * 2));
    unsigned short* wih0_lo = (unsigned short*)(ws + alloc((size_t)G4 * (EE + HH) * 2));
    unsigned short* whh0_hi = (unsigned short*)(ws + alloc((size_t)G4 * HH * 2));
    unsigned short* whh0_lo = (unsigned short*)(ws + alloc((size_t)G4 * HH * 2));
    unsigned short* wih1_hi = (unsigned short*)(ws + alloc((size_t)G4 * HH * 2));
    unsigned short* wih1_lo = (unsigned short*)(ws + alloc((size_t)G4 * HH * 2));
    unsigned short* whh1_hi = (unsigned short*)(ws + alloc((size_t)G4 * HH * 2));
    unsigned short* whh1_lo = (unsigned short*)(ws + alloc((size_t)G4 * HH * 2));
    unsigned short* wout_hi = (unsigned short*)(ws + alloc((size_t)VV * HH * 2));
    unsigned short* x_hi    = (unsigned short*)(ws + alloc((size_t)TT * BB * EE * 2));
    unsigned short* x_lo    = (unsigned short*)(ws + alloc((size_t)TT * BB * EE * 2));
    float*          xproj   = (float*)(ws + alloc((size_t)TT * BB * G4 * 4));
    unsigned short* feats_hi = (unsigned short*)(ws + alloc((size_t)TT * BB * HH * 2));
    unsigned short* feats_lo = (unsigned short*)(ws + alloc((size_t)TT * BB * HH * 2));
    float*          c0      = (float*)(ws + alloc((size_t)BB * HH * 4));
    float*          c1      = (float*)(ws + alloc((size_t)BB * HH * 4));
    unsigned short* h0a_hi  = (unsigned short*)(ws + alloc((size_t)BB * HH * 2));
    unsigned short* h0a_lo  = (unsigned short*)(ws + alloc((size_t)BB * HH * 2));
    unsigned short* h0b_hi  = (unsigned short*)(ws + alloc((size_t)BB * HH * 2));
    unsigned short* h0b_lo  = (unsigned short*)(ws + alloc((size_t)BB * HH * 2));
    unsigned short* h1i_hi  = (unsigned short*)(ws + alloc((size_t)BB * HH * 2));
    unsigned short* h1i_lo  = (unsigned short*)(ws + alloc((size_t)BB * HH * 2));
    unsigned short* zrow    = (unsigned short*)(ws + alloc((size_t)BB * HH * 2));
    float*          gbuf    = (float*)(ws + alloc((size_t)BB * G4 * 4));
    int*            cnt     = (int*)(ws + alloc(128 * 4));

    // 1) split-cast recurrence weights; plain-cast Wout
    cast_split<<<(2097152 + 255) / 256, 256, 0, stream>>>(Wih0, wih0_hi, wih0_lo, 2097152);
    cast_split<<<(1048576 + 255) / 256, 256, 0, stream>>>(Whh0, whh0_hi, whh0_lo, 1048576);
    cast_split<<<(1048576 + 255) / 256, 256, 0, stream>>>(Wih1, wih1_hi, wih1_lo, 1048576);
    cast_split<<<(1048576 + 255) / 256, 256, 0, stream>>>(Whh1, whh1_hi, whh1_lo, 1048576);
    cast_bf<<<(8192000 + 255) / 256, 256, 0, stream>>>(Wout, wout_hi, 8192000);

    // 2) embedding gather + split cast
    gather_embed<<<(TT * BB * EE / 8) / 256, 256, 0, stream>>>(ids, embed, x_hi, x_lo);

    // 3) state init (+ counters)
    init_state<<<64, 256, 0, stream>>>(ench, encc, c0, c1, h0a_hi, h0a_lo, h1i_hi, h1i_lo,
                                       zrow, cnt);

    // 4) hoisted input projection: xproj = x @ Wih0[:, :E]^T + bih0 + bhh0  (split x split)
    gemm_bt<true, true><<<dim3(2048 / 64, G4 / 64), 256, 0, stream>>>(
        x_hi, x_lo, EE, wih0_hi, wih0_lo, EE + HH, xproj, bih0, bhh0, G4, EE, 0);

    // 5) sequential recurrence: 2 launches per step, each on the full GPU (256 blocks x 512)
    for (int t = 0; t < TT; ++t) {
        const unsigned short* feedh = (t == 0) ? zrow : feats_hi + (size_t)(t - 1) * BB * HH;
        const unsigned short* feedl = (t == 0) ? zrow : feats_lo + (size_t)(t - 1) * BB * HH;
        const unsigned short* h0rdh = (t & 1) ? h0b_hi : h0a_hi;
        const unsigned short* h0rdl = (t & 1) ? h0b_lo : h0a_lo;
        unsigned short*       h0wrh = (t & 1) ? h0a_hi : h0b_hi;
        unsigned short*       h0wrl = (t & 1) ? h0a_lo : h0b_lo;
        // layer 0: gates = xproj[t] + feed @ Wih0[:,E:]^T + h0 @ Whh0^T
        lstm_gates<<<256, 512, 0, stream>>>(feedh, feedl, wih0_hi + 1024, wih0_lo + 1024, EE + HH,
                                            h0rdh, h0rdl, whh0_hi, whh0_lo, HH,
                                            xproj + (size_t)t * BB * G4, gbuf, nullptr, nullptr,
                                            c0, h0wrh, h0wrl, cnt);
        // layer 1: gates = h0_new @ Wih1^T + h1_prev @ Whh1^T + bih1 + bhh1
        const unsigned short* h1rdh = (t == 0) ? h1i_hi : feats_hi + (size_t)(t - 1) * BB * HH;
        const unsigned short* h1rdl = (t == 0) ? h1i_lo : feats_lo + (size_t)(t - 1) * BB * HH;
        lstm_gates<<<256, 512, 0, stream>>>(h0wrh, h0wrl, wih1_hi, wih1_lo, HH,
                                            h1rdh, h1rdl, whh1_hi, whh1_lo, HH,
                                            nullptr, gbuf, bih1, bhh1,
                                            c1, feats_hi + (size_t)t * BB * HH, feats_lo + (size_t)t * BB * HH,
                                            cnt + 64);
    }

    // 6) output projection: logits[b,t,:] = feats[t*16+b] @ Wout^T + bout   (plain bf16)
    gemm_bt<false, false><<<dim3(2048 / 64, VV / 64), 256, 0, stream>>>(
        feats_hi, nullptr, HH, wout_hi, nullptr, HH, out, bout, nullptr, VV, HH, 1);
}

// Round 3
// 7458.372 us; speedup vs baseline: 1.9440x; 1.9364x over previous
//
#include <hip/hip_runtime.h>

// Problem constants
#define TT 128
#define BB 16
#define HH 1024
#define EE 1024
#define VV 32000
#define G4 4096   // 4*H

using short8  = __attribute__((ext_vector_type(8))) short;
using floatx4 = __attribute__((ext_vector_type(4))) float;

__device__ __forceinline__ unsigned short f2bf(float f) {
    union { float f; unsigned u; } v; v.f = f;
    unsigned r = v.u + 0x7fffu + ((v.u >> 16) & 1u);
    return (unsigned short)(r >> 16);
}
__device__ __forceinline__ float bf2f(unsigned short u) {
    union { unsigned u; float f; } v; v.u = ((unsigned)u) << 16;
    return v.f;
}

// ---------------- fp32 -> bf16 plain cast, 4 elems/thread ----------------
__global__ void cast_bf(const float* __restrict__ src, unsigned short* __restrict__ dst, int n4) {
    int i = blockIdx.x * blockDim.x + threadIdx.x;
    if (i >= n4) return;
    float4 f = *(const float4*)(src + (size_t)i * 4);
    ushort4 o;
    o.x = f2bf(f.x); o.y = f2bf(f.y); o.z = f2bf(f.z); o.w = f2bf(f.w);
    *(ushort4*)(dst + (size_t)i * 4) = o;
}

// ---------------- fp32 -> (hi, lo) bf16 split cast, 4 elems/thread ----------------
__global__ void cast_split(const float* __restrict__ src, unsigned short* __restrict__ hi,
                           unsigned short* __restrict__ lo, int n4) {
    int i = blockIdx.x * blockDim.x + threadIdx.x;
    if (i >= n4) return;
    float4 f = *(const float4*)(src + (size_t)i * 4);
    ushort4 h, l;
    h.x = f2bf(f.x); l.x = f2bf(f.x - bf2f(h.x));
    h.y = f2bf(f.y); l.y = f2bf(f.y - bf2f(h.y));
    h.z = f2bf(f.z); l.z = f2bf(f.z - bf2f(h.z));
    h.w = f2bf(f.w); l.w = f2bf(f.w - bf2f(h.w));
    *(ushort4*)(hi + (size_t)i * 4) = h;
    *(ushort4*)(lo + (size_t)i * 4) = l;
}

// ---------------- embedding gather + split cast: x[t*16+b][e] ----------------
__global__ void gather_embed(const int* __restrict__ ids, const float* __restrict__ embed,
                             unsigned short* __restrict__ xhi, unsigned short* __restrict__ xlo) {
    int idx = blockIdx.x * blockDim.x + threadIdx.x;   // 2048*128 threads, 8 elems each
    int row = idx >> 7;              // t*16 + b
    int e0  = (idx & 127) << 3;
    int t = row >> 4, b = row & 15;
    int id = ids[b * TT + t];        // input_ids is [B, T]
    const float* s = embed + (size_t)id * EE + e0;
    float4 f0 = *(const float4*)s;
    float4 f1 = *(const float4*)(s + 4);
    float f[8] = {f0.x, f0.y, f0.z, f0.w, f1.x, f1.y, f1.z, f1.w};
    union { unsigned short u[8]; int4 v; } oh, ol;
#pragma unroll
    for (int j = 0; j < 8; ++j) {
        oh.u[j] = f2bf(f[j]);
        ol.u[j] = f2bf(f[j] - bf2f(oh.u[j]));
    }
    *(int4*)(xhi + (size_t)row * EE + e0) = oh.v;
    *(int4*)(xlo + (size_t)row * EE + e0) = ol.v;
}

// ---------------- state init (runs every call; ws is re-poisoned) ----------------
__global__ void init_state(const float* __restrict__ ench, const float* __restrict__ encc,
                           float* __restrict__ c0, float* __restrict__ c1,
                           unsigned short* __restrict__ h0ah, unsigned short* __restrict__ h0al,
                           unsigned short* __restrict__ h1ih, unsigned short* __restrict__ h1il,
                           unsigned short* __restrict__ zrow) {
    int i = blockIdx.x * blockDim.x + threadIdx.x;   // 16384
    c0[i] = encc[i];
    c1[i] = encc[16384 + i];
    float h0 = ench[i], h1 = ench[16384 + i];
    unsigned short h0h = f2bf(h0), h1h = f2bf(h1);
    h0ah[i] = h0h; h0al[i] = f2bf(h0 - bf2f(h0h));
    h1ih[i] = h1h; h1il[i] = f2bf(h1 - bf2f(h1h));
    zrow[i] = 0;
}

// ---------------- bf16 MFMA GEMM: C[M,N] = A[M,K] @ B[N,K]^T (+bias) ----------------
// Optional hi/lo split on A and/or B (3-product compensation).
// wave tile 16m x 64n, 4 waves on m -> block tile 64m x 64n.
// C/D: lane/reg r -> row = quad*4 + r, col = lane&15.
// outmode 0: row-major [M,N].  outmode 1: feats row m=t*16+b -> out[(b*TT+t)*N + n].
template<bool SA, bool SB>
__global__ void gemm_bt(const unsigned short* __restrict__ Ah, const unsigned short* __restrict__ Al, int lda,
                        const unsigned short* __restrict__ Bh, const unsigned short* __restrict__ Bl, int ldb,
                        float* __restrict__ C,
                        const float* __restrict__ bias1, const float* __restrict__ bias2,
                        int N, int K, int outmode) {
    int tid = threadIdx.x;
    int wave = tid >> 6, lane = tid & 63;
    int quad = lane >> 4, mcol = lane & 15;
    int m0 = blockIdx.x * 64 + wave * 16;
    int n0 = blockIdx.y * 64;
    floatx4 acc[4] = {};
    size_t aoff = (size_t)(m0 + mcol) * lda + quad * 8;
    size_t boff = (size_t)(n0 + mcol) * ldb + quad * 8;
    for (int k = 0; k < K; k += 32) {
        short8 ah = *(const short8*)(Ah + aoff + k);
        short8 al;
        if (SA) al = *(const short8*)(Al + aoff + k);
#pragma unroll
        for (int g = 0; g < 4; ++g) {
            size_t bo = boff + (size_t)g * 16 * ldb + k;
            short8 bh = *(const short8*)(Bh + bo);
            acc[g] = __builtin_amdgcn_mfma_f32_16x16x32_bf16(ah, bh, acc[g], 0, 0, 0);
            if (SB) {
                short8 bl = *(const short8*)(Bl + bo);
                acc[g] = __builtin_amdgcn_mfma_f32_16x16x32_bf16(ah, bl, acc[g], 0, 0, 0);
            }
            if (SA)
                acc[g] = __builtin_amdgcn_mfma_f32_16x16x32_bf16(al, bh, acc[g], 0, 0, 0);
        }
    }
#pragma unroll
    for (int g = 0; g < 4; ++g) {
#pragma unroll
        for (int r = 0; r < 4; ++r) {
            int m = m0 + quad * 4 + r;
            int n = n0 + g * 16 + mcol;
            float v = acc[g][r];
            if (bias1) v += bias1[n];
            if (bias2) v += bias2[n];
            size_t off;
            if (outmode == 0) off = (size_t)m * N + n;
            else { int t = m >> 4, b = m & 15; off = (size_t)(b * TT + t) * N + n; }
            C[off] = v;
        }
    }
}

// ---------------- one LSTM half-step: self-contained blocks, 16 waves ----------------
// grid 64 blocks x 1024 threads. Block = unit-group ug (16 hidden units, all 4 gates).
// Wave w (0..15): matrix m = w>>3 (0: A1@B1^T, 1: A2@B2^T), K-slice (w&7)*128.
// Each wave accumulates 4 gate tiles (16x16) over its K-slice; 16-wave LDS reduce;
// block-local pointwise cell. NO cross-block traffic, NO fences, NO counters.
__global__ __launch_bounds__(1024) void lstm_fused(
        const unsigned short* __restrict__ A1h, const unsigned short* __restrict__ A1l,
        const unsigned short* __restrict__ B1h, const unsigned short* __restrict__ B1l, int ldb1,
        const unsigned short* __restrict__ A2h, const unsigned short* __restrict__ A2l,
        const unsigned short* __restrict__ B2h, const unsigned short* __restrict__ B2l, int ldb2,
        const float* __restrict__ base,   // pre-accumulated input (layer0: xproj[t]) or null
        const float* __restrict__ bi1, const float* __restrict__ bi2,
        float* __restrict__ cstate,
        unsigned short* __restrict__ houth, unsigned short* __restrict__ houtl) {
    __shared__ float red[16][4][64][4];   // [wave][gate][lane][reg] = 64 KB exactly
    int tid = threadIdx.x, wave = tid >> 6, lane = tid & 63;
    int quad = lane >> 4, mcol = lane & 15;
    int u0 = blockIdx.x * 16;
    const unsigned short* Ah = (wave < 8) ? A1h : A2h;
    const unsigned short* Al = (wave < 8) ? A1l : A2l;
    const unsigned short* Bh = (wave < 8) ? B1h : B2h;
    const unsigned short* Bl = (wave < 8) ? B1l : B2l;
    int ldb   = (wave < 8) ? ldb1 : ldb2;
    int kbase = (wave & 7) * 128;
    floatx4 acc[4] = {};
    size_t aoff = (size_t)mcol * HH + kbase + quad * 8;
    size_t boff = (size_t)(u0 + mcol) * ldb + kbase + quad * 8;
#pragma unroll
    for (int k = 0; k < 128; k += 32) {
        short8 ah = *(const short8*)(Ah + aoff + k);
        short8 al = *(const short8*)(Al + aoff + k);
#pragma unroll
        for (int g = 0; g < 4; ++g) {
            size_t bo = boff + (size_t)g * 1024 * ldb + k;
            short8 bh = *(const short8*)(Bh + bo);
            short8 bl = *(const short8*)(Bl + bo);
            acc[g] = __builtin_amdgcn_mfma_f32_16x16x32_bf16(ah, bh, acc[g], 0, 0, 0);
            acc[g] = __builtin_amdgcn_mfma_f32_16x16x32_bf16(ah, bl, acc[g], 0, 0, 0);
            acc[g] = __builtin_amdgcn_mfma_f32_16x16x32_bf16(al, bh, acc[g], 0, 0, 0);
        }
    }
#pragma unroll
    for (int g = 0; g < 4; ++g)
        *(floatx4*)&red[wave][g][lane][0] = acc[g];
    __syncthreads();
    if (tid < 256) {
        // one thread per output element: row = batch, ui = unit-in-group
        int row = tid >> 4, ui = tid & 15, u = u0 + ui;
        int rl = (row >> 2) * 16 + ui, rr = row & 3;   // acc layout: row=quad*4+reg, col=mcol
        float gv[4];
#pragma unroll
        for (int g = 0; g < 4; ++g) {
            float s = 0.f;
#pragma unroll
            for (int w = 0; w < 16; ++w) s += red[w][g][rl][rr];
            int n = g * 1024 + u;
            if (base) s += base[(size_t)row * G4 + n];
            if (bi1)  s += bi1[n] + bi2[n];
            gv[g] = s;
        }
        float cold = cstate[(size_t)row * HH + u];
        float si = 1.f / (1.f + __expf(-gv[0]));
        float sf = 1.f / (1.f + __expf(-gv[1]));
        float tg = tanhf(gv[2]);
        float so = 1.f / (1.f + __expf(-gv[3]));
        float cn = sf * cold + si * tg;
        float hn = so * tanhf(cn);
        cstate[(size_t)row * HH + u] = cn;
        size_t hoff = (size_t)row * HH + u;
        unsigned short hh = f2bf(hn);
        houth[hoff] = hh;
        houtl[hoff] = f2bf(hn - bf2f(hh));
    }
}

extern "C" void kernel_launch(void* const* d_in, const int* in_sizes, int n_in,
                              void* d_out, int out_size, void* d_ws, size_t ws_size,
                              hipStream_t stream) {
    const int*   ids   = (const int*)d_in[0];
    const float* ench  = (const float*)d_in[1];
    const float* encc  = (const float*)d_in[2];
    const float* embed = (const float*)d_in[3];
    const float* Wih0  = (const float*)d_in[4];
    const float* Whh0  = (const float*)d_in[5];
    const float* bih0  = (const float*)d_in[6];
    const float* bhh0  = (const float*)d_in[7];
    const float* Wih1  = (const float*)d_in[8];
    const float* Whh1  = (const float*)d_in[9];
    const float* bih1  = (const float*)d_in[10];
    const float* bhh1  = (const float*)d_in[11];
    const float* Wout  = (const float*)d_in[12];
    const float* bout  = (const float*)d_in[13];
    float* out = (float*)d_out;
    (void)in_sizes; (void)n_in; (void)out_size; (void)ws_size;

    // workspace layout (deterministic bump allocator, 256B aligned)
    char* ws = (char*)d_ws;
    size_t o = 0;
    auto alloc = [&](size_t bytes) { size_t r = o; o += (bytes + 255) & ~(size_t)255; return r; };
    unsigned short* wih0_hi = (unsigned short*)(ws + alloc((size_t)G4 * (EE + HH) * 2));
    unsigned short* wih0_lo = (unsigned short*)(ws + alloc((size_t)G4 * (EE + HH) * 2));
    unsigned short* whh0_hi = (unsigned short*)(ws + alloc((size_t)G4 * HH * 2));
    unsigned short* whh0_lo = (unsigned short*)(ws + alloc((size_t)G4 * HH * 2));
    unsigned short* wih1_hi = (unsigned short*)(ws + alloc((size_t)G4 * HH * 2));
    unsigned short* wih1_lo = (unsigned short*)(ws + alloc((size_t)G4 * HH * 2));
    unsigned short* whh1_hi = (unsigned short*)(ws + alloc((size_t)G4 * HH * 2));
    unsigned short* whh1_lo = (unsigned short*)(ws + alloc((size_t)G4 * HH * 2));
    unsigned short* wout_hi = (unsigned short*)(ws + alloc((size_t)VV * HH * 2));
    unsigned short* x_hi    = (unsigned short*)(ws + alloc((size_t)TT * BB * EE * 2));
    unsigned short* x_lo    = (unsigned short*)(ws + alloc((size_t)TT * BB * EE * 2));
    float*          xproj   = (float*)(ws + alloc((size_t)TT * BB * G4 * 4));
    unsigned short* feats_hi = (unsigned short*)(ws + alloc((size_t)TT * BB * HH * 2));
    unsigned short* feats_lo = (unsigned short*)(ws + alloc((size_t)TT * BB * HH * 2));
    float*          c0      = (float*)(ws + alloc((size_t)BB * HH * 4));
    float*          c1      = (float*)(ws + alloc((size_t)BB * HH * 4));
    unsigned short* h0a_hi  = (unsigned short*)(ws + alloc((size_t)BB * HH * 2));
    unsigned short* h0a_lo  = (unsigned short*)(ws + alloc((size_t)BB * HH * 2));
    unsigned short* h0b_hi  = (unsigned short*)(ws + alloc((size_t)BB * HH * 2));
    unsigned short* h0b_lo  = (unsigned short*)(ws + alloc((size_t)BB * HH * 2));
    unsigned short* h1i_hi  = (unsigned short*)(ws + alloc((size_t)BB * HH * 2));
    unsigned short* h1i_lo  = (unsigned short*)(ws + alloc((size_t)BB * HH * 2));
    unsigned short* zrow    = (unsigned short*)(ws + alloc((size_t)BB * HH * 2));

    // 1) split-cast recurrence weights; plain-cast Wout
    cast_split<<<(2097152 + 255) / 256, 256, 0, stream>>>(Wih0, wih0_hi, wih0_lo, 2097152);
    cast_split<<<(1048576 + 255) / 256, 256, 0, stream>>>(Whh0, whh0_hi, whh0_lo, 1048576);
    cast_split<<<(1048576 + 255) / 256, 256, 0, stream>>>(Wih1, wih1_hi, wih1_lo, 1048576);
    cast_split<<<(1048576 + 255) / 256, 256, 0, stream>>>(Whh1, whh1_hi, whh1_lo, 1048576);
    cast_bf<<<(8192000 + 255) / 256, 256, 0, stream>>>(Wout, wout_hi, 8192000);

    // 2) embedding gather + split cast
    gather_embed<<<(TT * BB * EE / 8) / 256, 256, 0, stream>>>(ids, embed, x_hi, x_lo);

    // 3) state init
    init_state<<<64, 256, 0, stream>>>(ench, encc, c0, c1, h0a_hi, h0a_lo, h1i_hi, h1i_lo, zrow);

    // 4) hoisted input projection: xproj = x @ Wih0[:, :E]^T + bih0 + bhh0  (split x split)
    gemm_bt<true, true><<<dim3(2048 / 64, G4 / 64), 256, 0, stream>>>(
        x_hi, x_lo, EE, wih0_hi, wih0_lo, EE + HH, xproj, bih0, bhh0, G4, EE, 0);

    // 5) sequential recurrence: 2 launches per step, 64 blocks x 1024 threads each
    for (int t = 0; t < TT; ++t) {
        const unsigned short* feedh = (t == 0) ? zrow : feats_hi + (size_t)(t - 1) * BB * HH;
        const unsigned short* feedl = (t == 0) ? zrow : feats_lo + (size_t)(t - 1) * BB * HH;
        const unsigned short* h0rdh = (t & 1) ? h0b_hi : h0a_hi;
        const unsigned short* h0rdl = (t & 1) ? h0b_lo : h0a_lo;
        unsigned short*       h0wrh = (t & 1) ? h0a_hi : h0b_hi;
        unsigned short*       h0wrl = (t & 1) ? h0a_lo : h0b_lo;
        // layer 0: gates = xproj[t] + feed @ Wih0[:,E:]^T + h0 @ Whh0^T
        lstm_fused<<<64, 1024, 0, stream>>>(feedh, feedl, wih0_hi + 1024, wih0_lo + 1024, EE + HH,
                                            h0rdh, h0rdl, whh0_hi, whh0_lo, HH,
                                            xproj + (size_t)t * BB * G4, nullptr, nullptr,
                                            c0, h0wrh, h0wrl);
        // layer 1: gates = h0_new @ Wih1^T + h1_prev @ Whh1^T + bih1 + bhh1
        const unsigned short* h1rdh = (t == 0) ? h1i_hi : feats_hi + (size_t)(t - 1) * BB * HH;
        const unsigned short* h1rdl = (t == 0) ? h1i_lo : feats_lo + (size_t)(t - 1) * BB * HH;
        lstm_fused<<<64, 1024, 0, stream>>>(h0wrh, h0wrl, wih1_hi, wih1_lo, HH,
                                            h1rdh, h1rdl, whh1_hi, whh1_lo, HH,
                                            nullptr, bih1, bhh1,
                                            c1, feats_hi + (size_t)t * BB * HH, feats_lo + (size_t)t * BB * HH);
    }

    // 6) output projection: logits[b,t,:] = feats[t*16+b] @ Wout^T + bout   (plain bf16)
    gemm_bt<false, false><<<dim3(2048 / 64, VV / 64), 256, 0, stream>>>(
        feats_hi, nullptr, HH, wout_hi, nullptr, HH, out, bout, nullptr, VV, HH, 1);
}

// Round 5
// 5139.739 us; speedup vs baseline: 2.8210x; 1.4511x over previous
//
#include <hip/hip_runtime.h>

// Problem constants
#define TT 128
#define BB 16
#define HH 1024
#define EE 1024
#define VV 32000
#define G4 4096   // 4*H

using short8  = __attribute__((ext_vector_type(8))) short;
using floatx4 = __attribute__((ext_vector_type(4))) float;

__device__ __forceinline__ unsigned short f2bf(float f) {
    union { float f; unsigned u; } v; v.f = f;
    unsigned r = v.u + 0x7fffu + ((v.u >> 16) & 1u);
    return (unsigned short)(r >> 16);
}
__device__ __forceinline__ float bf2f(unsigned short u) {
    union { unsigned u; float f; } v; v.u = ((unsigned)u) << 16;
    return v.f;
}

// ---------------- fp32 -> bf16 plain cast, 4 elems/thread ----------------
__global__ void cast_bf(const float* __restrict__ src, unsigned short* __restrict__ dst, int n4) {
    int i = blockIdx.x * blockDim.x + threadIdx.x;
    if (i >= n4) return;
    float4 f = *(const float4*)(src + (size_t)i * 4);
    ushort4 o;
    o.x = f2bf(f.x); o.y = f2bf(f.y); o.z = f2bf(f.z); o.w = f2bf(f.w);
    *(ushort4*)(dst + (size_t)i * 4) = o;
}

// ---------------- fp32 -> (hi, lo) bf16 split cast, 4 elems/thread ----------------
__global__ void cast_split(const float* __restrict__ src, unsigned short* __restrict__ hi,
                           unsigned short* __restrict__ lo, int n4) {
    int i = blockIdx.x * blockDim.x + threadIdx.x;
    if (i >= n4) return;
    float4 f = *(const float4*)(src + (size_t)i * 4);
    ushort4 h, l;
    h.x = f2bf(f.x); l.x = f2bf(f.x - bf2f(h.x));
    h.y = f2bf(f.y); l.y = f2bf(f.y - bf2f(h.y));
    h.z = f2bf(f.z); l.z = f2bf(f.z - bf2f(h.z));
    h.w = f2bf(f.w); l.w = f2bf(f.w - bf2f(h.w));
    *(ushort4*)(hi + (size_t)i * 4) = h;
    *(ushort4*)(lo + (size_t)i * 4) = l;
}

// ---------------- embedding gather + split cast: x[t*16+b][e] ----------------
__global__ void gather_embed(const int* __restrict__ ids, const float* __restrict__ embed,
                             unsigned short* __restrict__ xhi, unsigned short* __restrict__ xlo) {
    int idx = blockIdx.x * blockDim.x + threadIdx.x;   // 2048*128 threads, 8 elems each
    int row = idx >> 7;              // t*16 + b
    int e0  = (idx & 127) << 3;
    int t = row >> 4, b = row & 15;
    int id = ids[b * TT + t];        // input_ids is [B, T]
    const float* s = embed + (size_t)id * EE + e0;
    float4 f0 = *(const float4*)s;
    float4 f1 = *(const float4*)(s + 4);
    float f[8] = {f0.x, f0.y, f0.z, f0.w, f1.x, f1.y, f1.z, f1.w};
    union { unsigned short u[8]; int4 v; } oh, ol;
#pragma unroll
    for (int j = 0; j < 8; ++j) {
        oh.u[j] = f2bf(f[j]);
        ol.u[j] = f2bf(f[j] - bf2f(oh.u[j]));
    }
    *(int4*)(xhi + (size_t)row * EE + e0) = oh.v;
    *(int4*)(xlo + (size_t)row * EE + e0) = ol.v;
}

// ---------------- state init (runs every call; ws is re-poisoned) ----------------
__global__ void init_state(const float* __restrict__ ench, const float* __restrict__ encc,
                           float* __restrict__ c0, float* __restrict__ c1,
                           unsigned short* __restrict__ h0ah, unsigned short* __restrict__ h0al,
                           unsigned short* __restrict__ h1ih, unsigned short* __restrict__ h1il,
                           unsigned short* __restrict__ zrow) {
    int i = blockIdx.x * blockDim.x + threadIdx.x;   // 16384
    c0[i] = encc[i];
    c1[i] = encc[16384 + i];
    float h0 = ench[i], h1 = ench[16384 + i];
    unsigned short h0h = f2bf(h0), h1h = f2bf(h1);
    h0ah[i] = h0h; h0al[i] = f2bf(h0 - bf2f(h0h));
    h1ih[i] = h1h; h1il[i] = f2bf(h1 - bf2f(h1h));
    zrow[i] = 0;
}

// ---------------- bf16 MFMA GEMM: C[M,N] = A[M,K] @ B[N,K]^T (+bias) ----------------
// Optional hi/lo split on A and/or B (3-product compensation).
// wave tile 16m x 64n, 4 waves on m -> block tile 64m x 64n.
// C/D: lane/reg r -> row = quad*4 + r, col = lane&15.
// outmode 0: row-major [M,N].  outmode 1: feats row m=t*16+b -> out[(b*TT+t)*N + n].
template<bool SA, bool SB>
__global__ void gemm_bt(const unsigned short* __restrict__ Ah, const unsigned short* __restrict__ Al, int lda,
                        const unsigned short* __restrict__ Bh, const unsigned short* __restrict__ Bl, int ldb,
                        float* __restrict__ C,
                        const float* __restrict__ bias1, const float* __restrict__ bias2,
                        int N, int K, int outmode) {
    int tid = threadIdx.x;
    int wave = tid >> 6, lane = tid & 63;
    int quad = lane >> 4, mcol = lane & 15;
    int m0 = blockIdx.x * 64 + wave * 16;
    int n0 = blockIdx.y * 64;
    floatx4 acc[4] = {};
    size_t aoff = (size_t)(m0 + mcol) * lda + quad * 8;
    size_t boff = (size_t)(n0 + mcol) * ldb + quad * 8;
    for (int k = 0; k < K; k += 32) {
        short8 ah = *(const short8*)(Ah + aoff + k);
        short8 al;
        if (SA) al = *(const short8*)(Al + aoff + k);
#pragma unroll
        for (int g = 0; g < 4; ++g) {
            size_t bo = boff + (size_t)g * 16 * ldb + k;
            short8 bh = *(const short8*)(Bh + bo);
            acc[g] = __builtin_amdgcn_mfma_f32_16x16x32_bf16(ah, bh, acc[g], 0, 0, 0);
            if (SB) {
                short8 bl = *(const short8*)(Bl + bo);
                acc[g] = __builtin_amdgcn_mfma_f32_16x16x32_bf16(ah, bl, acc[g], 0, 0, 0);
            }
            if (SA)
                acc[g] = __builtin_amdgcn_mfma_f32_16x16x32_bf16(al, bh, acc[g], 0, 0, 0);
        }
    }
#pragma unroll
    for (int g = 0; g < 4; ++g) {
#pragma unroll
        for (int r = 0; r < 4; ++r) {
            int m = m0 + quad * 4 + r;
            int n = n0 + g * 16 + mcol;
            float v = acc[g][r];
            if (bias1) v += bias1[n];
            if (bias2) v += bias2[n];
            size_t off;
            if (outmode == 0) off = (size_t)m * N + n;
            else { int t = m >> 4, b = m & 15; off = (size_t)(b * TT + t) * N + n; }
            C[off] = v;
        }
    }
}

// ---------------- LSTM gate GEMM: gate-split across the full GPU ----------------
// grid 256 blocks x 1024 threads. Block: gate g = bid>>6, unit-group ug = bid&63.
// Block EXCLUSIVELY owns its (g,ug) 16x16 pre-activation tile -> no cross-block sync.
// 16 waves: wave w handles matrix (w>>3) [1: A1@B1^T, 2: A2@B2^T], K-slice (w&7)*128.
// LDS reduce 16 waves, add base (xproj for layer 0), plain store to gbuf.
__global__ __launch_bounds__(1024) void lstm_gates(
        const unsigned short* __restrict__ A1h, const unsigned short* __restrict__ A1l,
        const unsigned short* __restrict__ B1h, const unsigned short* __restrict__ B1l, int ldb1,
        const unsigned short* __restrict__ A2h, const unsigned short* __restrict__ A2l,
        const unsigned short* __restrict__ B2h, const unsigned short* __restrict__ B2l, int ldb2,
        const float* __restrict__ base,   // pre-accumulated input (layer0: xproj[t]) or null
        float* __restrict__ gbuf) {       // [16][4096] pre-activation gates
    __shared__ float red[16][64][4];   // [wave][lane][reg] = 16 KB
    int tid = threadIdx.x, wave = tid >> 6, lane = tid & 63;
    int quad = lane >> 4, mcol = lane & 15;
    int g  = blockIdx.x >> 6;
    int ug = blockIdx.x & 63;
    int u0 = ug * 16;
    const unsigned short* Ah = (wave < 8) ? A1h : A2h;
    const unsigned short* Al = (wave < 8) ? A1l : A2l;
    const unsigned short* Bh = (wave < 8) ? B1h : B2h;
    const unsigned short* Bl = (wave < 8) ? B1l : B2l;
    int ldb   = (wave < 8) ? ldb1 : ldb2;
    int kbase = (wave & 7) * 128;
    floatx4 acc = {};
    size_t aoff = (size_t)mcol * HH + kbase + quad * 8;
    size_t boff = (size_t)(g * 1024 + u0 + mcol) * ldb + kbase + quad * 8;
#pragma unroll
    for (int k = 0; k < 128; k += 32) {
        short8 ah = *(const short8*)(Ah + aoff + k);
        short8 al = *(const short8*)(Al + aoff + k);
        short8 bh = *(const short8*)(Bh + boff + k);
        short8 bl = *(const short8*)(Bl + boff + k);
        acc = __builtin_amdgcn_mfma_f32_16x16x32_bf16(ah, bh, acc, 0, 0, 0);
        acc = __builtin_amdgcn_mfma_f32_16x16x32_bf16(ah, bl, acc, 0, 0, 0);
        acc = __builtin_amdgcn_mfma_f32_16x16x32_bf16(al, bh, acc, 0, 0, 0);
    }
    *(floatx4*)&red[wave][lane][0] = acc;
    __syncthreads();
    if (tid < 256) {
        // one thread per output element: row = batch, ui = unit-in-group
        int row = tid >> 4, ui = tid & 15;
        int rl = (row >> 2) * 16 + ui, rr = row & 3;   // acc layout: row=quad*4+reg, col=mcol
        float s = 0.f;
#pragma unroll
        for (int w = 0; w < 16; ++w) s += red[w][rl][rr];
        int n = g * 1024 + u0 + ui;
        if (base) s += base[(size_t)row * G4 + n];
        gbuf[(size_t)row * G4 + n] = s;
    }
}

// ---------------- pointwise LSTM cell: 64 blocks x 256 threads ----------------
__global__ void lstm_cell(const float* __restrict__ gbuf,
                          const float* __restrict__ bi1, const float* __restrict__ bi2,
                          float* __restrict__ cstate,
                          unsigned short* __restrict__ houth, unsigned short* __restrict__ houtl) {
    int i = blockIdx.x * blockDim.x + threadIdx.x;   // 16384
    int row = i >> 10, u = i & 1023;
    float gv[4];
#pragma unroll
    for (int g = 0; g < 4; ++g) {
        int n = g * 1024 + u;
        float v = gbuf[(size_t)row * G4 + n];
        if (bi1) v += bi1[n] + bi2[n];
        gv[g] = v;
    }
    float cold = cstate[(size_t)row * HH + u];
    float si = 1.f / (1.f + __expf(-gv[0]));
    float sf = 1.f / (1.f + __expf(-gv[1]));
    float tg = tanhf(gv[2]);
    float so = 1.f / (1.f + __expf(-gv[3]));
    float cn = sf * cold + si * tg;
    float hn = so * tanhf(cn);
    cstate[(size_t)row * HH + u] = cn;
    size_t hoff = (size_t)row * HH + u;
    unsigned short hh = f2bf(hn);
    houth[hoff] = hh;
    houtl[hoff] = f2bf(hn - bf2f(hh));
}

extern "C" void kernel_launch(void* const* d_in, const int* in_sizes, int n_in,
                              void* d_out, int out_size, void* d_ws, size_t ws_size,
                              hipStream_t stream) {
    const int*   ids   = (const int*)d_in[0];
    const float* ench  = (const float*)d_in[1];
    const float* encc  = (const float*)d_in[2];
    const float* embed = (const float*)d_in[3];
    const float* Wih0  = (const float*)d_in[4];
    const float* Whh0  = (const float*)d_in[5];
    const float* bih0  = (const float*)d_in[6];
    const float* bhh0  = (const float*)d_in[7];
    const float* Wih1  = (const float*)d_in[8];
    const float* Whh1  = (const float*)d_in[9];
    const float* bih1  = (const float*)d_in[10];
    const float* bhh1  = (const float*)d_in[11];
    const float* Wout  = (const float*)d_in[12];
    const float* bout  = (const float*)d_in[13];
    float* out = (float*)d_out;
    (void)in_sizes; (void)n_in; (void)out_size; (void)ws_size;

    // workspace layout (deterministic bump allocator, 256B aligned)
    char* ws = (char*)d_ws;
    size_t o = 0;
    auto alloc = [&](size_t bytes) { size_t r = o; o += (bytes + 255) & ~(size_t)255; return r; };
    unsigned short* wih0_hi = (unsigned short*)(ws + alloc((size_t)G4 * (EE + HH) * 2));
    unsigned short* wih0_lo = (unsigned short*)(ws + alloc((size_t)G4 * (EE + HH) * 2));
    unsigned short* whh0_hi = (unsigned short*)(ws + alloc((size_t)G4 * HH * 2));
    unsigned short* whh0_lo = (unsigned short*)(ws + alloc((size_t)G4 * HH * 2));
    unsigned short* wih1_hi = (unsigned short*)(ws + alloc((size_t)G4 * HH * 2));
    unsigned short* wih1_lo = (unsigned short*)(ws + alloc((size_t)G4 * HH * 2));
    unsigned short* whh1_hi = (unsigned short*)(ws + alloc((size_t)G4 * HH * 2));
    unsigned short* whh1_lo = (unsigned short*)(ws + alloc((size_t)G4 * HH * 2));
    unsigned short* wout_hi = (unsigned short*)(ws + alloc((size_t)VV * HH * 2));
    unsigned short* x_hi    = (unsigned short*)(ws + alloc((size_t)TT * BB * EE * 2));
    unsigned short* x_lo    = (unsigned short*)(ws + alloc((size_t)TT * BB * EE * 2));
    float*          xproj   = (float*)(ws + alloc((size_t)TT * BB * G4 * 4));
    unsigned short* feats_hi = (unsigned short*)(ws + alloc((size_t)TT * BB * HH * 2));
    unsigned short* feats_lo = (unsigned short*)(ws + alloc((size_t)TT * BB * HH * 2));
    float*          c0      = (float*)(ws + alloc((size_t)BB * HH * 4));
    float*          c1      = (float*)(ws + alloc((size_t)BB * HH * 4));
    unsigned short* h0a_hi  = (unsigned short*)(ws + alloc((size_t)BB * HH * 2));
    unsigned short* h0a_lo  = (unsigned short*)(ws + alloc((size_t)BB * HH * 2));
    unsigned short* h0b_hi  = (unsigned short*)(ws + alloc((size_t)BB * HH * 2));
    unsigned short* h0b_lo  = (unsigned short*)(ws + alloc((size_t)BB * HH * 2));
    unsigned short* h1i_hi  = (unsigned short*)(ws + alloc((size_t)BB * HH * 2));
    unsigned short* h1i_lo  = (unsigned short*)(ws + alloc((size_t)BB * HH * 2));
    unsigned short* zrow    = (unsigned short*)(ws + alloc((size_t)BB * HH * 2));
    float*          gbufA   = (float*)(ws + alloc((size_t)BB * G4 * 4));
    float*          gbufB   = (float*)(ws + alloc((size_t)BB * G4 * 4));

    // 1) split-cast recurrence weights; plain-cast Wout
    cast_split<<<(2097152 + 255) / 256, 256, 0, stream>>>(Wih0, wih0_hi, wih0_lo, 2097152);
    cast_split<<<(1048576 + 255) / 256, 256, 0, stream>>>(Whh0, whh0_hi, whh0_lo, 1048576);
    cast_split<<<(1048576 + 255) / 256, 256, 0, stream>>>(Wih1, wih1_hi, wih1_lo, 1048576);
    cast_split<<<(1048576 + 255) / 256, 256, 0, stream>>>(Whh1, whh1_hi, whh1_lo, 1048576);
    cast_bf<<<(8192000 + 255) / 256, 256, 0, stream>>>(Wout, wout_hi, 8192000);

    // 2) embedding gather + split cast
    gather_embed<<<(TT * BB * EE / 8) / 256, 256, 0, stream>>>(ids, embed, x_hi, x_lo);

    // 3) state init
    init_state<<<64, 256, 0, stream>>>(ench, encc, c0, c1, h0a_hi, h0a_lo, h1i_hi, h1i_lo, zrow);

    // 4) hoisted input projection: xproj = x @ Wih0[:, :E]^T + bih0 + bhh0  (split x split)
    gemm_bt<true, true><<<dim3(2048 / 64, G4 / 64), 256, 0, stream>>>(
        x_hi, x_lo, EE, wih0_hi, wih0_lo, EE + HH, xproj, bih0, bhh0, G4, EE, 0);

    // 5) sequential recurrence: 4 launches per step (gates0, cell0, gates1, cell1)
    for (int t = 0; t < TT; ++t) {
        const unsigned short* feedh = (t == 0) ? zrow : feats_hi + (size_t)(t - 1) * BB * HH;
        const unsigned short* feedl = (t == 0) ? zrow : feats_lo + (size_t)(t - 1) * BB * HH;
        const unsigned short* h0rdh = (t & 1) ? h0b_hi : h0a_hi;
        const unsigned short* h0rdl = (t & 1) ? h0b_lo : h0a_lo;
        unsigned short*       h0wrh = (t & 1) ? h0a_hi : h0b_hi;
        unsigned short*       h0wrl = (t & 1) ? h0a_lo : h0b_lo;
        // layer 0: gates = xproj[t] + feed @ Wih0[:,E:]^T + h0 @ Whh0^T
        lstm_gates<<<256, 1024, 0, stream>>>(feedh, feedl, wih0_hi + 1024, wih0_lo + 1024, EE + HH,
                                             h0rdh, h0rdl, whh0_hi, whh0_lo, HH,
                                             xproj + (size_t)t * BB * G4, gbufA);
        lstm_cell<<<64, 256, 0, stream>>>(gbufA, nullptr, nullptr, c0, h0wrh, h0wrl);
        // layer 1: gates = h0_new @ Wih1^T + h1_prev @ Whh1^T + bih1 + bhh1
        const unsigned short* h1rdh = (t == 0) ? h1i_hi : feats_hi + (size_t)(t - 1) * BB * HH;
        const unsigned short* h1rdl = (t == 0) ? h1i_lo : feats_lo + (size_t)(t - 1) * BB * HH;
        lstm_gates<<<256, 1024, 0, stream>>>(h0wrh, h0wrl, wih1_hi, wih1_lo, HH,
                                             h1rdh, h1rdl, whh1_hi, whh1_lo, HH,
                                             nullptr, gbufB);
        lstm_cell<<<64, 256, 0, stream>>>(gbufB, bih1, bhh1, c1,
                                          feats_hi + (size_t)t * BB * HH, feats_lo + (size_t)t * BB * HH);
    }

    // 6) output projection: logits[b,t,:] = feats[t*16+b] @ Wout^T + bout   (plain bf16)
    gemm_bt<false, false><<<dim3(2048 / 64, VV / 64), 256, 0, stream>>>(
        feats_hi, nullptr, HH, wout_hi, nullptr, HH, out, bout, nullptr, VV, HH, 1);
}